// Round 4
// baseline (3167.154 us; speedup 1.0000x reference)
//
#include <hip/hip_runtime.h>
#include <hip/hip_cooperative_groups.h>
#include <math.h>

namespace cg = cooperative_groups;

// ---------------- types ----------------
typedef __attribute__((ext_vector_type(8))) short bf16x8;
typedef __attribute__((ext_vector_type(4))) short short4v;
typedef __attribute__((ext_vector_type(4))) float f32x4;

__device__ __forceinline__ float sigm(float x) { return 1.f / (1.f + expf(-x)); }

__device__ __forceinline__ float bf2f(short x) {
    unsigned u = ((unsigned)(unsigned short)x) << 16;
    float f; __builtin_memcpy(&f, &u, 4); return f;
}
__device__ __forceinline__ short f2bf(float f) {
    unsigned u; __builtin_memcpy(&u, &f, 4);
    unsigned r = (u + 0x7fffu + ((u >> 16) & 1u)) >> 16;
    return (short)r;
}

// ---------------- workspace layout (byte offsets) ----------------
#define OFF_C1      0u           // (unused now)
#define OFF_C2      262144u      // (unused now)
#define OFF_H2A     524288u      // 2 x 64x1024 bf16  262144  (h2 double buffer)
#define OFF_H1HI    786432u      // 33 x 64x1024 bf16  4325376
#define OFF_H1LO    5111808u     // 33 x 64x1024 bf16  4325376
#define OFF_H1F     9437184u     // 32 x 64x1024 f32   8388608
#define OFF_X0HI    17825792u    // 2048x1024 bf16 4194304  (aliased by VHI later)
#define OFF_X0LO    22020096u    // 2048x1024 bf16 4194304  (aliased by VLO later)
#define OFF_B1      26214400u    // 4096 f32 16384
#define OFF_B2      26230784u    // 4096 f32 16384
#define OFF_WHH1HI  26247168u    // 4096x1024 bf16 8388608
#define OFF_WHH1LO  34635776u
#define OFF_WIH1HI  43024384u
#define OFF_WIH1LO  51412992u
#define OFF_WHH2HI  59801600u
#define OFF_WVHI    68190208u
#define OFF_WVLO    76578816u
#define OFF_WH2HI   84967424u
#define OFF_X12     93356032u    // 2048x4096 f32 33554432 (also lo-dump during prep)
// total ~121 MB

// ---------------- prep kernels ----------------
__global__ __launch_bounds__(256) void zero_ws(float4* __restrict__ p) {
    int i = blockIdx.x * 256 + threadIdx.x;
    p[i] = make_float4(0.f, 0.f, 0.f, 0.f);
}

// 4096 x 1024 slice of src (row stride rs, col offset co), gate-interleaved rows
// (dst row j' = d*4+g from src row g*1024+d), split into hi/lo bf16.
__global__ __launch_bounds__(256) void perm_w_split(const float* __restrict__ src,
                                                    short* __restrict__ hi,
                                                    short* __restrict__ lo,
                                                    int rs, int co) {
    int idx = blockIdx.x * 256 + threadIdx.x;   // 4096 blocks
    int jp = idx >> 8;
    int kq = idx & 255;
    int jsrc = (jp & 3) * 1024 + (jp >> 2);
    float4 v = *(const float4*)(src + (size_t)jsrc * rs + co + kq * 4);
    float a[4] = {v.x, v.y, v.z, v.w};
    short4v h, l;
    #pragma unroll
    for (int e = 0; e < 4; e++) {
        short q = f2bf(a[e]);
        h[e] = q;
        l[e] = f2bf(a[e] - bf2f(q));
    }
    *(short4v*)(hi + (size_t)jp * 1024 + kq * 4) = h;
    *(short4v*)(lo + (size_t)jp * 1024 + kq * 4) = l;
}

__global__ __launch_bounds__(256) void bias_prep(
    const float* __restrict__ bi1, const float* __restrict__ bh1,
    const float* __restrict__ bi2, const float* __restrict__ bh2,
    float* __restrict__ b1p, float* __restrict__ b2p) {
    int jp = blockIdx.x * 256 + threadIdx.x;     // 16 blocks
    int j = (jp & 3) * 1024 + (jp >> 2);
    b1p[jp] = bi1[j] + bh1[j];
    b2p[jp] = bi2[j] + bh2[j];
}

__global__ __launch_bounds__(256) void gather_x0_split(
    const int* __restrict__ tokens, const float* __restrict__ emb,
    short* __restrict__ hi, short* __restrict__ lo) {
    int idx = blockIdx.x * 256 + threadIdx.x;    // 2048 blocks
    int p = idx >> 8;
    int k0 = (idx & 255) * 4;
    int tok = tokens[p];
    float4 v = *(const float4*)(emb + (size_t)tok * 1024 + k0);
    float a[4] = {v.x, v.y, v.z, v.w};
    short4v h, l;
    #pragma unroll
    for (int e = 0; e < 4; e++) {
        short q = f2bf(a[e]);
        h[e] = q;
        l[e] = f2bf(a[e] - bf2f(q));
    }
    *(short4v*)(hi + (size_t)p * 1024 + k0) = h;
    *(short4v*)(lo + (size_t)p * 1024 + k0) = l;
}

// ---------------- big GEMM: C[2048][4096] = sum_seg Aseg @ Bseg^T + bias -------
__global__ __launch_bounds__(256) void big_gemm(
    const short* __restrict__ A0, const short* __restrict__ A1s,
    const short* __restrict__ A2s, const short* __restrict__ A3s,
    const short* __restrict__ B0, const short* __restrict__ B1s,
    const short* __restrict__ B2s, const short* __restrict__ B3s,
    const float* __restrict__ bias, float* __restrict__ C, int K) {
    __shared__ short As[128 * 40];
    __shared__ short Bs[128 * 40];
    int tid = threadIdx.x;
    int n0 = blockIdx.x * 128;
    int m0 = blockIdx.y * 128;
    int lane = tid & 63, w = tid >> 6;
    int wm = (w >> 1) * 64, wn = (w & 1) * 64;
    int quad = lane >> 4, l16 = lane & 15;
    int srow = tid >> 2;           // 0..63
    int skc = (tid & 3) * 8;       // k chunk within BK

    f32x4 acc[4][4];
    f32x4 z4 = {0.f, 0.f, 0.f, 0.f};
    #pragma unroll
    for (int i = 0; i < 4; i++)
        #pragma unroll
        for (int j = 0; j < 4; j++) acc[i][j] = z4;

    for (int k0 = 0; k0 < K; k0 += 32) {
        int seg = k0 >> 10;
        const short* Ab = (seg == 0) ? A0 : (seg == 1) ? A1s : (seg == 2) ? A2s : A3s;
        const short* Bb = (seg == 0) ? B0 : (seg == 1) ? B1s : (seg == 2) ? B2s : B3s;
        int kk = (k0 & 1023) + skc;
        const short* ga = Ab + (size_t)(m0 + srow) * 1024 + kk;
        const short* gb = Bb + (size_t)(n0 + srow) * 1024 + kk;
        bf16x8 av0 = *(const bf16x8*)ga;
        bf16x8 av1 = *(const bf16x8*)(ga + 64 * 1024);
        bf16x8 bv0 = *(const bf16x8*)gb;
        bf16x8 bv1 = *(const bf16x8*)(gb + 64 * 1024);
        __syncthreads();
        *(bf16x8*)&As[srow * 40 + skc] = av0;
        *(bf16x8*)&As[(srow + 64) * 40 + skc] = av1;
        *(bf16x8*)&Bs[srow * 40 + skc] = bv0;
        *(bf16x8*)&Bs[(srow + 64) * 40 + skc] = bv1;
        __syncthreads();
        bf16x8 af[4], bfr[4];
        #pragma unroll
        for (int im = 0; im < 4; im++)
            af[im] = *(const bf16x8*)&As[(wm + im * 16 + l16) * 40 + quad * 8];
        #pragma unroll
        for (int in = 0; in < 4; in++)
            bfr[in] = *(const bf16x8*)&Bs[(wn + in * 16 + l16) * 40 + quad * 8];
        #pragma unroll
        for (int im = 0; im < 4; im++)
            #pragma unroll
            for (int in = 0; in < 4; in++)
                acc[im][in] = __builtin_amdgcn_mfma_f32_16x16x32_bf16(
                    af[im], bfr[in], acc[im][in], 0, 0, 0);
    }
    #pragma unroll
    for (int in = 0; in < 4; in++) {
        int j = n0 + wn + in * 16 + l16;
        float bsv = bias[j];
        #pragma unroll
        for (int im = 0; im < 4; im++) {
            #pragma unroll
            for (int r = 0; r < 4; r++) {
                int p = m0 + wm + im * 16 + quad * 4 + r;
                C[(size_t)p * 4096 + j] = acc[im][in][r] + bsv;
            }
        }
    }
}

// ---------------- persistent layer-1 recurrence (cooperative) ----------------
// 256 blocks x 256 thr. Block b owns 16 gate-interleaved columns j' = b*16..+16
// (d = b*4+dl, all 4 gates). W hi/lo fragments live in registers (loaded once).
// Per step: A-frags from Hhi/Hlo slot t, 96 MFMAs/wave (triple split),
// LDS split-K reduce, fp32 LSTM epilogue (c in registers), write slot t+1, grid sync.
__global__ __launch_bounds__(256) void pcell1(
    const short* __restrict__ Whi, const short* __restrict__ Wlo,
    const float* __restrict__ Xg, short* __restrict__ Hhi,
    short* __restrict__ Hlo, float* __restrict__ Hf) {
    __shared__ float red[4096];
    cg::grid_group grid = cg::this_grid();
    int tid = threadIdx.x;
    int lane = tid & 63, w = tid >> 6;
    int quad = lane >> 4, l16 = lane & 15;
    int b = blockIdx.x;
    int kbase = w * 256;

    bf16x8 whi[8], wlo[8];
    {
        const short* wp = Whi + (size_t)(b * 16 + l16) * 1024 + kbase + quad * 8;
        const short* lp = Wlo + (size_t)(b * 16 + l16) * 1024 + kbase + quad * 8;
        #pragma unroll
        for (int i = 0; i < 8; i++) {
            whi[i] = *(const bf16x8*)(wp + i * 32);
            wlo[i] = *(const bf16x8*)(lp + i * 32);
        }
    }
    int s_e = tid >> 2, dl = tid & 3;
    int d = b * 4 + dl;
    float c_reg = 0.f;

    for (int t = 0; t < 32; t++) {
        const short* ah = Hhi + (size_t)t * 65536 + (size_t)l16 * 1024 + kbase + quad * 8;
        const short* al = Hlo + (size_t)t * 65536 + (size_t)l16 * 1024 + kbase + quad * 8;
        f32x4 acc[4];
        f32x4 z4 = {0.f, 0.f, 0.f, 0.f};
        acc[0] = z4; acc[1] = z4; acc[2] = z4; acc[3] = z4;
        #pragma unroll
        for (int i = 0; i < 8; i++) {
            int k = i * 32;
            #pragma unroll
            for (int mt = 0; mt < 4; mt++) {
                bf16x8 Ah = *(const bf16x8*)(ah + mt * 16384 + k);
                bf16x8 Al = *(const bf16x8*)(al + mt * 16384 + k);
                acc[mt] = __builtin_amdgcn_mfma_f32_16x16x32_bf16(Ah, whi[i], acc[mt], 0, 0, 0);
                acc[mt] = __builtin_amdgcn_mfma_f32_16x16x32_bf16(Al, whi[i], acc[mt], 0, 0, 0);
                acc[mt] = __builtin_amdgcn_mfma_f32_16x16x32_bf16(Ah, wlo[i], acc[mt], 0, 0, 0);
            }
        }
        __syncthreads();
        #pragma unroll
        for (int mt = 0; mt < 4; mt++)
            #pragma unroll
            for (int r = 0; r < 4; r++)
                red[(w * 64 + mt * 16 + quad * 4 + r) * 16 + l16] = acc[mt][r];
        __syncthreads();
        float gi = 0.f, gf = 0.f, gg = 0.f, go = 0.f;
        #pragma unroll
        for (int w2 = 0; w2 < 4; w2++) {
            const float* rp = &red[(w2 * 64 + s_e) * 16 + dl * 4];
            gi += rp[0]; gf += rp[1]; gg += rp[2]; go += rp[3];
        }
        float4 xg = *(const float4*)(Xg + (size_t)(t * 64 + s_e) * 4096 + b * 16 + dl * 4);
        gi += xg.x; gf += xg.y; gg += xg.z; go += xg.w;
        float cn = sigm(gf) * c_reg + sigm(gi) * tanhf(gg);
        c_reg = cn;
        float hn = sigm(go) * tanhf(cn);
        short q = f2bf(hn);
        size_t o = (size_t)(t + 1) * 65536 + (size_t)s_e * 1024 + d;
        Hhi[o] = q;
        Hlo[o] = f2bf(hn - bf2f(q));
        Hf[(size_t)t * 65536 + (size_t)s_e * 1024 + d] = hn;
        grid.sync();
    }
}

// ---------------- persistent layer-2 recurrence (cooperative, single bf16) ----
__global__ __launch_bounds__(256) void pcell2(
    const short* __restrict__ Whi, const float* __restrict__ Xg,
    short* __restrict__ H2, float* __restrict__ out) {
    __shared__ float red[4096];
    cg::grid_group grid = cg::this_grid();
    int tid = threadIdx.x;
    int lane = tid & 63, w = tid >> 6;
    int quad = lane >> 4, l16 = lane & 15;
    int b = blockIdx.x;
    int kbase = w * 256;

    bf16x8 whi[8];
    {
        const short* wp = Whi + (size_t)(b * 16 + l16) * 1024 + kbase + quad * 8;
        #pragma unroll
        for (int i = 0; i < 8; i++) whi[i] = *(const bf16x8*)(wp + i * 32);
    }
    int s_e = tid >> 2, dl = tid & 3;
    int d = b * 4 + dl;
    float c_reg = 0.f;

    for (int t = 0; t < 32; t++) {
        const short* ah = H2 + (size_t)(t & 1) * 65536 + (size_t)l16 * 1024 + kbase + quad * 8;
        f32x4 acc[4];
        f32x4 z4 = {0.f, 0.f, 0.f, 0.f};
        acc[0] = z4; acc[1] = z4; acc[2] = z4; acc[3] = z4;
        #pragma unroll
        for (int i = 0; i < 8; i++) {
            int k = i * 32;
            #pragma unroll
            for (int mt = 0; mt < 4; mt++) {
                bf16x8 Ah = *(const bf16x8*)(ah + mt * 16384 + k);
                acc[mt] = __builtin_amdgcn_mfma_f32_16x16x32_bf16(Ah, whi[i], acc[mt], 0, 0, 0);
            }
        }
        __syncthreads();
        #pragma unroll
        for (int mt = 0; mt < 4; mt++)
            #pragma unroll
            for (int r = 0; r < 4; r++)
                red[(w * 64 + mt * 16 + quad * 4 + r) * 16 + l16] = acc[mt][r];
        __syncthreads();
        float gi = 0.f, gf = 0.f, gg = 0.f, go = 0.f;
        #pragma unroll
        for (int w2 = 0; w2 < 4; w2++) {
            const float* rp = &red[(w2 * 64 + s_e) * 16 + dl * 4];
            gi += rp[0]; gf += rp[1]; gg += rp[2]; go += rp[3];
        }
        float4 xg = *(const float4*)(Xg + (size_t)(t * 64 + s_e) * 4096 + b * 16 + dl * 4);
        gi += xg.x; gf += xg.y; gg += xg.z; go += xg.w;
        float cn = sigm(gf) * c_reg + sigm(gi) * tanhf(gg);
        c_reg = cn;
        float hn = sigm(go) * tanhf(cn);
        H2[(size_t)((t + 1) & 1) * 65536 + (size_t)s_e * 1024 + d] = f2bf(hn);
        out[(size_t)t * 65536 + (size_t)s_e * 1024 + d] = hn;
        grid.sync();
    }
}

// ---------------- batched attention (fp32) ----------------
__global__ __launch_bounds__(256) void attn_batch(
    const float* __restrict__ H1f, const float* __restrict__ F,
    short* __restrict__ Vhi, short* __restrict__ Vlo) {
    __shared__ float vs[4][4][1024];
    int n = blockIdx.x, tg = blockIdx.y;
    int tid = threadIdx.x, lane = tid & 63, w = tid >> 6;

    float h[4][16];
    #pragma unroll
    for (int tt = 0; tt < 4; tt++) {
        const float* hp = H1f + ((size_t)((tg * 4 + tt) * 64 + n)) * 1024 + lane * 16;
        #pragma unroll
        for (int j = 0; j < 4; j++) {
            float4 v = *(const float4*)(hp + j * 4);
            h[tt][j * 4 + 0] = v.x; h[tt][j * 4 + 1] = v.y;
            h[tt][j * 4 + 2] = v.z; h[tt][j * 4 + 3] = v.w;
        }
    }
    float vacc[4][16];
    #pragma unroll
    for (int tt = 0; tt < 4; tt++)
        #pragma unroll
        for (int j = 0; j < 16; j++) vacc[tt][j] = 0.f;

    const float* Fn = F + ((size_t)n * 196) * 1024 + lane * 16;
    for (int l = w; l < 196; l += 4) {
        const float* fr = Fn + (size_t)l * 1024;
        float f[16];
        #pragma unroll
        for (int j = 0; j < 4; j++) {
            float4 v = *(const float4*)(fr + j * 4);
            f[j * 4 + 0] = v.x; f[j * 4 + 1] = v.y;
            f[j * 4 + 2] = v.z; f[j * 4 + 3] = v.w;
        }
        float p[4] = {0.f, 0.f, 0.f, 0.f};
        #pragma unroll
        for (int tt = 0; tt < 4; tt++)
            #pragma unroll
            for (int j = 0; j < 16; j++) p[tt] += f[j] * h[tt][j];
        #pragma unroll
        for (int off = 32; off > 0; off >>= 1) {
            #pragma unroll
            for (int tt = 0; tt < 4; tt++) p[tt] += __shfl_xor(p[tt], off, 64);
        }
        #pragma unroll
        for (int tt = 0; tt < 4; tt++)
            #pragma unroll
            for (int j = 0; j < 16; j++) vacc[tt][j] += p[tt] * f[j];
    }
    #pragma unroll
    for (int tt = 0; tt < 4; tt++)
        #pragma unroll
        for (int j4 = 0; j4 < 4; j4++) {
            float4 v;
            v.x = vacc[tt][j4 * 4 + 0]; v.y = vacc[tt][j4 * 4 + 1];
            v.z = vacc[tt][j4 * 4 + 2]; v.w = vacc[tt][j4 * 4 + 3];
            *(float4*)&vs[w][tt][lane * 16 + j4 * 4] = v;
        }
    __syncthreads();
    int d0 = tid * 4;
    #pragma unroll
    for (int tt = 0; tt < 4; tt++) {
        float4 a = *(const float4*)&vs[0][tt][d0];
        float4 b = *(const float4*)&vs[1][tt][d0];
        float4 cc = *(const float4*)&vs[2][tt][d0];
        float4 e = *(const float4*)&vs[3][tt][d0];
        float sv[4];
        sv[0] = a.x + b.x + cc.x + e.x;
        sv[1] = a.y + b.y + cc.y + e.y;
        sv[2] = a.z + b.z + cc.z + e.z;
        sv[3] = a.w + b.w + cc.w + e.w;
        short4v b1, b2;
        #pragma unroll
        for (int e2 = 0; e2 < 4; e2++) {
            short q = f2bf(sv[e2]);
            b1[e2] = q;
            b2[e2] = f2bf(sv[e2] - bf2f(q));
        }
        size_t row = ((size_t)(tg * 4 + tt) * 64 + n) * 1024 + d0;
        *(short4v*)(Vhi + row) = b1;
        *(short4v*)(Vlo + row) = b2;
    }
}

// ---------------- host launch ----------------
extern "C" void kernel_launch(void* const* d_in, const int* in_sizes, int n_in,
                              void* d_out, int out_size, void* d_ws, size_t ws_size,
                              hipStream_t stream) {
    const int*   tokens = (const int*)d_in[0];
    const float* imgf   = (const float*)d_in[1];
    const float* emb    = (const float*)d_in[2];
    const float* w_ih1  = (const float*)d_in[3];
    const float* w_hh1  = (const float*)d_in[4];
    const float* b_ih1  = (const float*)d_in[5];
    const float* b_hh1  = (const float*)d_in[6];
    const float* w_ih2  = (const float*)d_in[7];
    const float* w_hh2  = (const float*)d_in[8];
    const float* b_ih2  = (const float*)d_in[9];
    const float* b_hh2  = (const float*)d_in[10];
    float* out = (float*)d_out;
    char* ws = (char*)d_ws;

    short* H2     = (short*)(ws + OFF_H2A);
    short* H1hi   = (short*)(ws + OFF_H1HI);
    short* H1lo   = (short*)(ws + OFF_H1LO);
    float* H1f    = (float*)(ws + OFF_H1F);
    short* X0hi   = (short*)(ws + OFF_X0HI);
    short* X0lo   = (short*)(ws + OFF_X0LO);
    short* Vhi    = (short*)(ws + OFF_X0HI);   // alias (X0 dead after X1 GEMM)
    short* Vlo    = (short*)(ws + OFF_X0LO);
    float* bias1p = (float*)(ws + OFF_B1);
    float* bias2p = (float*)(ws + OFF_B2);
    short* whh1hi = (short*)(ws + OFF_WHH1HI);
    short* whh1lo = (short*)(ws + OFF_WHH1LO);
    short* wih1hi = (short*)(ws + OFF_WIH1HI);
    short* wih1lo = (short*)(ws + OFF_WIH1LO);
    short* whh2hi = (short*)(ws + OFF_WHH2HI);
    short* wvhi   = (short*)(ws + OFF_WVHI);
    short* wvlo   = (short*)(ws + OFF_WVLO);
    short* wh2hi  = (short*)(ws + OFF_WH2HI);
    float* X12    = (float*)(ws + OFF_X12);
    short* dump   = (short*)(ws + OFF_X12);    // prep-time scratch, overwritten later

    // prep
    zero_ws<<<64, 256, 0, stream>>>((float4*)(ws + OFF_H2A));    // h2 both slots
    zero_ws<<<32, 256, 0, stream>>>((float4*)(ws + OFF_H1HI));   // H1hi slot 0
    zero_ws<<<32, 256, 0, stream>>>((float4*)(ws + OFF_H1LO));   // H1lo slot 0
    perm_w_split<<<4096, 256, 0, stream>>>(w_hh1, whh1hi, whh1lo, 1024, 0);
    perm_w_split<<<4096, 256, 0, stream>>>(w_ih1, wih1hi, wih1lo, 1024, 0);
    perm_w_split<<<4096, 256, 0, stream>>>(w_hh2, whh2hi, dump, 1024, 0);
    perm_w_split<<<4096, 256, 0, stream>>>(w_ih2, wvhi, wvlo, 2048, 0);
    perm_w_split<<<4096, 256, 0, stream>>>(w_ih2, wh2hi, dump, 2048, 1024);
    bias_prep<<<16, 256, 0, stream>>>(b_ih1, b_hh1, b_ih2, b_hh2, bias1p, bias2p);
    gather_x0_split<<<2048, 256, 0, stream>>>(tokens, emb, X0hi, X0lo);

    // X1 = (X0hi+X0lo) @ (wih1hi+wih1lo)^T + bias1, triple-split, K=3072
    big_gemm<<<dim3(32, 16), 256, 0, stream>>>(
        X0hi, X0lo, X0hi, X0hi,
        wih1hi, wih1hi, wih1lo, wih1hi,
        bias1p, X12, 3072);

    // layer-1 recurrence: one cooperative kernel, 32 steps
    {
        const short* a_whi = whh1hi;
        const short* a_wlo = whh1lo;
        const float* a_xg  = X12;
        void* args[] = {(void*)&a_whi, (void*)&a_wlo, (void*)&a_xg,
                        (void*)&H1hi, (void*)&H1lo, (void*)&H1f};
        hipLaunchCooperativeKernel((void*)pcell1, dim3(256), dim3(256), args, 0, stream);
    }

    // batched attention (fp32 in, compensated double-bf16 out)
    attn_batch<<<dim3(64, 8), 256, 0, stream>>>(H1f, imgf, Vhi, Vlo);

    // X2 = v@wv (triple-split) + h1@wh + bias2, K=4096
    big_gemm<<<dim3(32, 16), 256, 0, stream>>>(
        Vhi, Vlo, Vhi, H1hi + 65536,
        wvhi, wvhi, wvlo, wh2hi,
        bias2p, X12, 4096);

    // layer-2 recurrence: one cooperative kernel, 32 steps
    {
        const short* a_w  = whh2hi;
        const float* a_xg = X12;
        void* args[] = {(void*)&a_w, (void*)&a_xg, (void*)&H2, (void*)&out};
        hipLaunchCooperativeKernel((void*)pcell2, dim3(256), dim3(256), args, 0, stream);
    }
}